// Round 7
// baseline (229.019 us; speedup 1.0000x reference)
//
#include <hip/hip_runtime.h>
#include <hip/hip_bf16.h>
#include <stdint.h>

// Problem dims (fixed by reference)
#define HH 224
#define WW 224
#define CC 1024
#define BB 256
#define KK (HH*WW)            // 50176
#define EPSILON_F 0.001f
#define LOG2E 1.4426950408889634f
#define INVN (1.0f/50176.0f)
// clip(v,+-2000)/N == clip(v/N, +-2000/N) since 1/N > 0
#define CLAMP_V (2000.0f/50176.0f)

// Tile: 256m x 64c x 1568k per block; 4 waves, each 64m x 64c. grid = 16 c x 32 z = 512.
// R7 structure: BARRIER-FREE main loop.
//   R6 evidence: atomics exonerated (stores+reduce ~= atomics), memory exonerated
//   (FETCH 25 MB), yet 103 us with MfmaUtil 10% -> per-step LDS-barrier + vmcnt drain
//   with only 8 waves/CU was ~70% stall. B is COMPUTED, not loaded: each lane now
//   generates its own B fragment in registers (ExA[4][8] cached per wb, 4 Ey exps/step),
//   so Bs LDS and both per-step barriers are deleted. Waves run as independent
//   software-pipelined streams; MFMA (310cyc) and B-gen VALU (~260cyc) overlap on
//   separate pipes (m114).
#define KCHUNKS 32
#define ROWS_PER_CHUNK 7
#define WBS 7                 // 224/32 k-blocks per row

typedef __bf16 bf16x8 __attribute__((ext_vector_type(8)));
typedef float  f32x4  __attribute__((ext_vector_type(4)));

// ---------------- reduce: out[i] += sum over 31 ws partial copies --------------------------
__global__ __launch_bounds__(256)
void reduce_kernel(const float* __restrict__ part, float* __restrict__ out) {
    int i = blockIdx.x * 256 + threadIdx.x;          // 65536 float4 slots
    f32x4 s = ((const f32x4*)out)[i];                // copy 0 lives in d_out
#pragma unroll
    for (int z = 0; z < KCHUNKS - 1; ++z)
        s += ((const f32x4*)part)[(size_t)z * (BB * CC / 4) + i];
    ((f32x4*)out)[i] = s;
}

// ---------------- main fused curve-gen + GEMM ---------------------------------------------
// NOTE: no min-waves arg in __launch_bounds__ (R2: (256,7) spilled the accumulator).
template <bool PARTIAL>
__global__ __launch_bounds__(256)
void blob_gemm_kernel(const float* __restrict__ x,
                      const float* __restrict__ pos,
                      const float* __restrict__ sig,
                      const float* __restrict__ cwt,
                      const float* __restrict__ xs,
                      const float* __restrict__ ys,
                      float* __restrict__ out,
                      float* __restrict__ part) {
    __shared__ float xrow[WW];              // x_axis
    __shared__ float ycol[ROWS_PER_CHUNK];  // y_axis values for this chunk

    const int tid  = threadIdx.x;
    const int wave = tid >> 6;
    const int lane = tid & 63;

    // XCD-locality swizzle (R5/R6 proven: FETCH 200->25MB): xcd = id%8 owns 4 k-chunks.
    const int id   = blockIdx.x;
    const int xcd  = id & 7;
    const int slot = id >> 3;                 // 0..63
    const int z    = xcd * 4 + (slot & 3);    // k-chunk 0..31
    const int cx   = slot >> 2;               // c-tile 0..15
    const int c0   = cx * 64;
    const int k0   = z * (ROWS_PER_CHUNK * WW);

    if (tid < WW) xrow[tid] = xs[tid];
    if (tid >= WW && tid < WW + ROWS_PER_CHUNK)
        ycol[tid - WW] = ys[(z * ROWS_PER_CHUNK + (tid - WW)) * WW];
    __syncthreads();   // the ONLY barrier

    // fragment lane mapping (identical pattern for A and B operands):
    // lane holds op[row = lane&15][k = (lane>>4)*8 + j]
    const int fl = lane & 15;
    const int fk = (lane >> 4) * 8;
    const int wm = wave * 64;

    // ---- per-lane B params for its 4 c's: c = c0 + ni*16 + fl ----
    float A2[4], S2[4], P0[4], P1[4];
#pragma unroll
    for (int ni = 0; ni < 4; ++ni) {
        int c = c0 + ni * 16 + fl;
        float s  = sig[c];
        float w  = cwt[c];
        float s2 = s * s;
        A2[ni] = w / (6.283185307179586f * s2 + EPSILON_F) * INVN;
        S2[ni] = LOG2E / (2.0f * s2 + EPSILON_F);
        P0[ni] = pos[2 * c];
        P1[ni] = pos[2 * c + 1];
    }

    // y-axis into registers
    float ycolr[ROWS_PER_CHUNK];
#pragma unroll
    for (int r = 0; r < ROWS_PER_CHUNK; ++r) ycolr[r] = ycol[r];

    // ---- A fragment base (direct global fp32, cvt in-register) ----
    const float* aff = x + (size_t)(wm + fl) * KK + k0 + fk;

    // ---- ExA cache: exp2(-dx^2*S2)*A2 for this lane's 8 k-positions x 4 c's ----
    float ExA[4][8];
    auto refresh_ex = [&](int wb) {
        float4 xa = *(const float4*)(xrow + wb * 32 + fk);
        float4 xb = *(const float4*)(xrow + wb * 32 + fk + 4);
        float xv[8] = {xa.x, xa.y, xa.z, xa.w, xb.x, xb.y, xb.z, xb.w};
#pragma unroll
        for (int ni = 0; ni < 4; ++ni)
#pragma unroll
            for (int j = 0; j < 8; ++j) {
                float dx = xv[j] - P1[ni];
                ExA[ni][j] = __builtin_amdgcn_exp2f(-(dx * S2[ni] * dx)) * A2[ni];
            }
    };
    refresh_ex(0);

    auto cvt_frag = [](float4 f0, float4 f1) -> bf16x8 {
        union { __bf16 h[8]; bf16x8 v; } t;
        t.h[0] = (__bf16)f0.x; t.h[1] = (__bf16)f0.y;
        t.h[2] = (__bf16)f0.z; t.h[3] = (__bf16)f0.w;
        t.h[4] = (__bf16)f1.x; t.h[5] = (__bf16)f1.y;
        t.h[6] = (__bf16)f1.z; t.h[7] = (__bf16)f1.w;
        return t.v;
    };

    f32x4 acc[4][4];
#pragma unroll
    for (int i = 0; i < 4; ++i)
#pragma unroll
        for (int j = 0; j < 4; ++j) acc[i][j] = (f32x4){0.f, 0.f, 0.f, 0.f};

    // prologue: load A fragments for step 0
    float4 pf0[4], pf1[4];
#pragma unroll
    for (int mi = 0; mi < 4; ++mi) {
        const float* p = aff + (size_t)mi * 16 * KK;
        pf0[mi] = *(const float4*)(p);
        pf1[mi] = *(const float4*)(p + 4);
    }
    bf16x8 fa[4];
#pragma unroll
    for (int mi = 0; mi < 4; ++mi) fa[mi] = cvt_frag(pf0[mi], pf1[mi]);

    // ---- barrier-free main loop: 49 steps, r fast / wb slow ----
#pragma unroll 1
    for (int wb = 0; wb < WBS; ++wb) {
#pragma unroll
        for (int r = 0; r < ROWS_PER_CHUNK; ++r) {
            const bool last = (wb == WBS - 1) && (r == ROWS_PER_CHUNK - 1);

            // 1. issue next step's A loads (one step of register prefetch)
            if (!last) {
                int nr = r + 1, nwb = wb;
                if (nr == ROWS_PER_CHUNK) { nr = 0; ++nwb; }
                const int koff = nr * WW + nwb * 32;
#pragma unroll
                for (int mi = 0; mi < 4; ++mi) {
                    const float* p = aff + (size_t)mi * 16 * KK + koff;
                    pf0[mi] = *(const float4*)(p);
                    pf1[mi] = *(const float4*)(p + 4);
                }
            }

            // 2. generate B fragments in registers (no LDS, no barrier)
            bf16x8 fb[4];
#pragma unroll
            for (int ni = 0; ni < 4; ++ni) {
                float dy = ycolr[r] - P0[ni];
                float ey = __builtin_amdgcn_exp2f(-(dy * S2[ni] * dy));
                union { __bf16 h[8]; bf16x8 v; } t;
#pragma unroll
                for (int j = 0; j < 8; ++j) {
                    float v = ExA[ni][j] * ey;
                    t.h[j] = (__bf16)__builtin_amdgcn_fmed3f(v, -CLAMP_V, CLAMP_V);
                }
                fb[ni] = t.v;
            }

            // 3. 16 MFMAs
#pragma unroll
            for (int mi = 0; mi < 4; ++mi)
#pragma unroll
                for (int ni = 0; ni < 4; ++ni)
                    acc[mi][ni] = __builtin_amdgcn_mfma_f32_16x16x32_bf16(
                        fa[mi], fb[ni], acc[mi][ni], 0, 0, 0);

            // 4. convert prefetched A; refresh ExA at wb boundary
            if (!last) {
#pragma unroll
                for (int mi = 0; mi < 4; ++mi) fa[mi] = cvt_frag(pf0[mi], pf1[mi]);
                if (r == ROWS_PER_CHUNK - 1) refresh_ex(wb + 1);
            }
        }
    }

    // ---- epilogue: C/D layout col=lane&15, row=(lane>>4)*4+reg ----
    // PARTIAL: plain stores; chunk z -> copy z (copy 0 = d_out, z>0 -> ws slab z-1).
    const int orow = (lane >> 4) * 4;
    float* base;
    if (PARTIAL) base = (z == 0) ? out : (part + (size_t)(z - 1) * BB * CC);
    else         base = out;
#pragma unroll
    for (int mi = 0; mi < 4; ++mi) {
        int m = wm + mi * 16 + orow;
#pragma unroll
        for (int ni = 0; ni < 4; ++ni) {
            int cc = c0 + ni * 16 + fl;
#pragma unroll
            for (int v = 0; v < 4; ++v) {
                if (PARTIAL)
                    base[(size_t)(m + v) * CC + cc] = acc[mi][ni][v];
                else
                    atomicAdd(base + (size_t)(m + v) * CC + cc, acc[mi][ni][v]);
            }
        }
    }
}

extern "C" void kernel_launch(void* const* d_in, const int* in_sizes, int n_in,
                              void* d_out, int out_size, void* d_ws, size_t ws_size,
                              hipStream_t stream) {
    const float* x   = (const float*)d_in[0];
    const float* pos = (const float*)d_in[1];
    const float* sg  = (const float*)d_in[2];
    const float* cw  = (const float*)d_in[3];
    const float* xs  = (const float*)d_in[4];
    const float* ys  = (const float*)d_in[5];
    float* out = (float*)d_out;

    const int nblk = 16 * KCHUNKS;                              // 512
    const size_t PSZ = (size_t)(KCHUNKS - 1) * BB * CC * 4;     // 31 MiB

    if (ws_size >= PSZ) {
        float* part = (float*)d_ws;
        // every partial copy (incl. d_out as copy 0) is fully overwritten -> no memset
        blob_gemm_kernel<true><<<nblk, 256, 0, stream>>>(x, pos, sg, cw, xs, ys, out, part);
        reduce_kernel<<<BB * CC / 4 / 256, 256, 0, stream>>>(part, out);
    } else {
        hipMemsetAsync(out, 0, (size_t)BB * CC * sizeof(float), stream);
        blob_gemm_kernel<false><<<nblk, 256, 0, stream>>>(x, pos, sg, cw, xs, ys, out, nullptr);
    }
}

// Round 8
// 171.825 us; speedup vs baseline: 1.3329x; 1.3329x over previous
//
#include <hip/hip_runtime.h>
#include <hip/hip_bf16.h>
#include <stdint.h>

// Problem dims (fixed by reference)
#define HH 224
#define WW 224
#define CC 1024
#define BB 256
#define KK (HH*WW)            // 50176
#define EPSILON_F 0.001f
#define LOG2E 1.4426950408889634f
#define INVN (1.0f/50176.0f)
// clip(v,+-2000)/N == clip(v/N, +-2000/N) since 1/N > 0
#define CLAMP_V (2000.0f/50176.0f)

// R8 = R4's skeleton (the best measured structure: LDS-staged A+B, double-buffered,
// ONE barrier/step — 1.7k cyc/block-step vs 2.5-3.9k for all register-direct-A variants;
// R5/R6/R7 evidence: per-lane A-fragment gathers are the hidden serializer) with R4's two
// bounds fixed:
//   1. fp32 fetch (R4: 200 MB = 58/69 us) -> bf16 prepass; ws in [33.5,59.2) MB proven,
//      xb (25.7 MB) + atomic epilogue fits (R5 vs R6: atomics >= stores+reduce).
//   2. occupancy (R4: 47 KB LDS -> 3 blocks/CU) -> tile 128m x 64c, LDS 28.5 KB
//      -> 4-5 blocks/CU; grid = 2m x 16c x 56z = 1792 blocks.
//   3. R5-proven XCD swizzle: each XCD owns 7 k-chunks -> 3.2 MB A slice, L2-resident.
#define KCHUNKS 56
#define ROWS_PER_CHUNK 4
#define STEPS 28              // r fast (4), wb slow (7)

// 36 elems = 72 B rows: b128 reads of 16 consecutive rows -> bank starts all distinct,
// <=2-way overlap (free, m136); staging writes <=2-way.
#define LDS_STRIDE 36

typedef __bf16 bf16x8 __attribute__((ext_vector_type(8)));
typedef float  f32x4  __attribute__((ext_vector_type(4)));

// ---------------- prepass: x fp32 -> bf16 -------------------------------------------------
__global__ __launch_bounds__(256)
void cvt_bf16_kernel(const float* __restrict__ x, __hip_bfloat16* __restrict__ xb, int n8) {
    int i = blockIdx.x * 256 + threadIdx.x;   // one thread per 8 elements
    if (i >= n8) return;
    const float4* p = (const float4*)(x + (size_t)i * 8);
    float4 a = p[0], b = p[1];
    union { __hip_bfloat16 h[8]; uint4 u; } o;
    o.h[0] = (__hip_bfloat16)a.x; o.h[1] = (__hip_bfloat16)a.y;
    o.h[2] = (__hip_bfloat16)a.z; o.h[3] = (__hip_bfloat16)a.w;
    o.h[4] = (__hip_bfloat16)b.x; o.h[5] = (__hip_bfloat16)b.y;
    o.h[6] = (__hip_bfloat16)b.z; o.h[7] = (__hip_bfloat16)b.w;
    *(uint4*)(xb + (size_t)i * 8) = o.u;
}

// ---------------- main fused curve-gen + GEMM ---------------------------------------------
// NOTE: no min-waves arg in __launch_bounds__ (R2: (256,7) spilled the accumulator).
template <bool BF16A>
__global__ __launch_bounds__(256)
void blob_gemm_kernel(const void* __restrict__ xin,
                      const float* __restrict__ pos,
                      const float* __restrict__ sig,
                      const float* __restrict__ cwt,
                      const float* __restrict__ xs,
                      const float* __restrict__ ys,
                      float* __restrict__ out) {
    __shared__ __bf16 As[2][128 * LDS_STRIDE];  // A tile: 128 m-rows x 32 k, dbuf
    __shared__ __bf16 Bs[2][64 * LDS_STRIDE];   // B^T tile: 64 c-rows x 32 k, dbuf
    __shared__ float  xrow[WW];
    __shared__ float  ycol[ROWS_PER_CHUNK];

    const int tid  = threadIdx.x;
    const int wave = tid >> 6;
    const int lane = tid & 63;

    // XCD-locality swizzle (R5/R6 proven): xcd = id%8 owns k-chunks [xcd*7, xcd*7+7).
    const int id   = blockIdx.x;
    const int xcd  = id & 7;
    const int slot = id >> 3;                  // 0..223
    const int z    = xcd * 7 + slot % 7;       // k-chunk 0..55
    const int rest = slot / 7;                 // 0..31
    const int cx   = rest & 15;                // c-tile 0..15
    const int mt   = rest >> 4;                // m-tile 0..1
    const int c0   = cx * 64;
    const int m0   = mt * 128;
    const int k0   = z * (ROWS_PER_CHUNK * WW);

    if (tid < WW) xrow[tid] = xs[tid];                 // x_axis
    if (tid >= WW && tid < WW + ROWS_PER_CHUNK)
        ycol[tid - WW] = ys[(z * ROWS_PER_CHUNK + (tid - WW)) * WW];  // y_axis

    // ---- per-thread curve params: one c per thread, one k-octet ----
    const int q   = tid & 3;            // k-octet within 32-wide step
    const int cr0 = tid >> 2;           // 0..63
    const int c   = c0 + cr0;
    float A2, S2, P0, P1;
    {
        float s  = sig[c];
        float w  = cwt[c];
        float s2 = s * s;
        A2 = w / (6.283185307179586f * s2 + EPSILON_F) * INVN;
        S2 = LOG2E / (2.0f * s2 + EPSILON_F);
        P0 = pos[2 * c];
        P1 = pos[2 * c + 1];
    }
    const int bs_w  = cr0 * LDS_STRIDE + q * 8;
    const int as_w0 = cr0 * LDS_STRIDE + q * 8;                 // A rows 0..63
    const int as_w1 = (64 + cr0) * LDS_STRIDE + q * 8;          // A rows 64..127

    // A staging global bases (thread-contiguous 16 B chunks — the R4-proven pattern)
    const __hip_bfloat16* agb0 = (const __hip_bfloat16*)xin + (size_t)(m0 + cr0) * KK + k0 + q * 8;
    const __hip_bfloat16* agb1 = (const __hip_bfloat16*)xin + (size_t)(m0 + 64 + cr0) * KK + k0 + q * 8;
    const float* agf0 = (const float*)xin + (size_t)(m0 + cr0) * KK + k0 + q * 8;
    const float* agf1 = (const float*)xin + (size_t)(m0 + 64 + cr0) * KK + k0 + q * 8;

    // wave tile: 2x2 arrangement of (64m x 32c)
    const int wm = (wave & 1) * 64;
    const int wn = (wave >> 1) * 32;
    const int fl = lane & 15;
    const int fk = (lane >> 4) * 8;
    const int ar_off = (wm + fl) * LDS_STRIDE + fk;
    const int br_off = (wn + fl) * LDS_STRIDE + fk;

    f32x4 acc[4][2];
#pragma unroll
    for (int i = 0; i < 4; ++i)
#pragma unroll
        for (int j = 0; j < 2; ++j) acc[i][j] = (f32x4){0.f, 0.f, 0.f, 0.f};

    __syncthreads();   // axes ready

    float ycolr[ROWS_PER_CHUNK];
#pragma unroll
    for (int r = 0; r < ROWS_PER_CHUNK; ++r) ycolr[r] = ycol[r];

    // ExA cache for this thread's 8 k-positions (refresh once per wb)
    float Ex[8];
    auto refresh_ex = [&](int wb) {
        float4 xa = *(const float4*)(xrow + wb * 32 + q * 8);
        float4 xb = *(const float4*)(xrow + wb * 32 + q * 8 + 4);
        float xv[8] = {xa.x, xa.y, xa.z, xa.w, xb.x, xb.y, xb.z, xb.w};
#pragma unroll
        for (int i = 0; i < 8; ++i) {
            float dx = xv[i] - P1;
            Ex[i] = __builtin_amdgcn_exp2f(-(dx * S2 * dx));
        }
    };

    auto gen_b = [&](int r) -> uint4 {
        float dy  = ycolr[r] - P0;
        float eyA = __builtin_amdgcn_exp2f(-(dy * S2 * dy)) * A2;
        union { __bf16 h[8]; uint4 u; } cv;
#pragma unroll
        for (int i = 0; i < 8; ++i) {
            float v = Ex[i] * eyA;
            cv.h[i] = (__bf16)__builtin_amdgcn_fmed3f(v, -CLAMP_V, CLAMP_V);
        }
        return cv.u;
    };

    auto cvt8 = [](float4 f0, float4 f1) -> uint4 {
        union { __bf16 h[8]; uint4 u; } t;
        t.h[0] = (__bf16)f0.x; t.h[1] = (__bf16)f0.y;
        t.h[2] = (__bf16)f0.z; t.h[3] = (__bf16)f0.w;
        t.h[4] = (__bf16)f1.x; t.h[5] = (__bf16)f1.y;
        t.h[6] = (__bf16)f1.z; t.h[7] = (__bf16)f1.w;
        return t.u;
    };

    // ---- stage step 0 into buffer 0 ----
    refresh_ex(0);
    {
        uint4 a0, a1;
        if (BF16A) {
            a0 = *(const uint4*)(agb0);
            a1 = *(const uint4*)(agb1);
        } else {
            a0 = cvt8(*(const float4*)(agf0), *(const float4*)(agf0 + 4));
            a1 = cvt8(*(const float4*)(agf1), *(const float4*)(agf1 + 4));
        }
        *(uint4*)(&Bs[0][bs_w])  = gen_b(0);
        *(uint4*)(&As[0][as_w0]) = a0;
        *(uint4*)(&As[0][as_w1]) = a1;
    }
    __syncthreads();   // buffer 0 ready

    // ---- main loop: compute buf(s&1); stage s+1 into other buf; ONE barrier/step ----
    // Safety: reads of buf X happen before the barrier of step s; writes to buf X happen
    // after that barrier (in step s+1) -> no race with a single barrier.
    int nr = 1, nwb = 0;   // (row, wb) of step s+1 being staged
#pragma unroll 2
    for (int s = 0; s < STEPS; ++s) {
        const int cb = s & 1;

        // 1. prefetch next A into registers (longest latency first)
        uint4 pa0, pa1;
        float4 pf00, pf01, pf10, pf11;
        if (s < STEPS - 1) {
            const int koff = nr * WW + nwb * 32;
            if (BF16A) {
                pa0 = *(const uint4*)(agb0 + koff);
                pa1 = *(const uint4*)(agb1 + koff);
            } else {
                pf00 = *(const float4*)(agf0 + koff);
                pf01 = *(const float4*)(agf0 + koff + 4);
                pf10 = *(const float4*)(agf1 + koff);
                pf11 = *(const float4*)(agf1 + koff + 4);
            }
        }

        // 2. fragments from LDS + 8 MFMAs
        bf16x8 fa[4], fb[2];
#pragma unroll
        for (int i = 0; i < 4; ++i)
            fa[i] = *(const bf16x8*)(&As[cb][ar_off + i * 16 * LDS_STRIDE]);
#pragma unroll
        for (int j = 0; j < 2; ++j)
            fb[j] = *(const bf16x8*)(&Bs[cb][br_off + j * 16 * LDS_STRIDE]);
#pragma unroll
        for (int mi = 0; mi < 4; ++mi)
#pragma unroll
            for (int ni = 0; ni < 2; ++ni)
                acc[mi][ni] = __builtin_amdgcn_mfma_f32_16x16x32_bf16(
                    fa[mi], fb[ni], acc[mi][ni], 0, 0, 0);

        // 3. stage step s+1 into the other buffer
        if (s < STEPS - 1) {
            if (nr == 0) refresh_ex(nwb);        // wave-uniform branch, once per wb
            uint4 cv = gen_b(nr);
            uint4 a0, a1;
            if (BF16A) {
                a0 = pa0; a1 = pa1;
            } else {
                a0 = cvt8(pf00, pf01);
                a1 = cvt8(pf10, pf11);
            }
            *(uint4*)(&Bs[cb ^ 1][bs_w])  = cv;
            *(uint4*)(&As[cb ^ 1][as_w0]) = a0;
            *(uint4*)(&As[cb ^ 1][as_w1]) = a1;
            ++nr;
            if (nr == ROWS_PER_CHUNK) { nr = 0; ++nwb; }
        }
        __syncthreads();
    }

    // ---- epilogue: C/D layout col=lane&15, row=(lane>>4)*4+reg -> atomicAdd (K-split) ----
    const int orow = (lane >> 4) * 4;
#pragma unroll
    for (int mi = 0; mi < 4; ++mi) {
        int m = m0 + wm + mi * 16 + orow;
#pragma unroll
        for (int ni = 0; ni < 2; ++ni) {
            int cc = c0 + wn + ni * 16 + fl;
#pragma unroll
            for (int v = 0; v < 4; ++v)
                atomicAdd(out + (size_t)(m + v) * CC + cc, acc[mi][ni][v]);
        }
    }
}

extern "C" void kernel_launch(void* const* d_in, const int* in_sizes, int n_in,
                              void* d_out, int out_size, void* d_ws, size_t ws_size,
                              hipStream_t stream) {
    const float* x   = (const float*)d_in[0];
    const float* pos = (const float*)d_in[1];
    const float* sg  = (const float*)d_in[2];
    const float* cw  = (const float*)d_in[3];
    const float* xs  = (const float*)d_in[4];
    const float* ys  = (const float*)d_in[5];
    float* out = (float*)d_out;

    // K-split partials accumulate via atomicAdd -> zero output first
    hipMemsetAsync(out, 0, (size_t)BB * CC * sizeof(float), stream);

    const int nblk = 2 * 16 * KCHUNKS;               // 1792
    const size_t nx = (size_t)BB * KK;
    const size_t XB = nx * sizeof(__hip_bfloat16);   // 25.7 MB (ws >= 33.5 MB proven R4)

    if (ws_size >= XB) {
        __hip_bfloat16* xb = (__hip_bfloat16*)d_ws;
        int n8 = (int)(nx / 8);
        cvt_bf16_kernel<<<(n8 + 255) / 256, 256, 0, stream>>>(x, xb, n8);
        blob_gemm_kernel<true><<<nblk, 256, 0, stream>>>(xb, pos, sg, cw, xs, ys, out);
    } else {
        blob_gemm_kernel<false><<<nblk, 256, 0, stream>>>(x, pos, sg, cw, xs, ys, out);
    }
}